// Round 1
// baseline (708.084 us; speedup 1.0000x reference)
//
#include <hip/hip_runtime.h>
#include <stdint.h>

#define BM 64
#define BN 64
#define BK 32

// ---------------------------------------------------------------------------
// Detect mask element width. jax bool may arrive as int32 (0/1), float32
// (0.0/1.0), or raw 1-byte bool. For 4-byte elements the nonzero test is the
// same at bit level for int and float, so we only need 4-byte vs 1-byte.
// Samples first 16384 words (64 KB <= min possible buffer size of 32 MB).
__global__ __launch_bounds__(256) void detect_mask_width(
    const unsigned int* __restrict__ m, int* __restrict__ esz_out) {
  __shared__ int s_ok;
  if (threadIdx.x == 0) s_ok = 1;
  __syncthreads();
  int ok = 1;
  for (int i = 0; i < 64; ++i) {
    unsigned int v = m[(size_t)threadIdx.x * 64 + i];
    if (!(v == 0u || v == 1u || v == 0x3F800000u)) ok = 0;
  }
  if (!ok) atomicAnd(&s_ok, 0);
  __syncthreads();
  if (threadIdx.x == 0) *esz_out = s_ok ? 4 : 1;
}

// ---------------------------------------------------------------------------
// Masked mean via sparse gather. One block (128 threads) per (row, mask_id).
// Phase 1: build 2048-bit membership bitmap with __ballot (wave 0 -> words
// 0..15, wave 1 -> words 16..31). Phase 2: thread 0 expands set bits into an
// LDS index list. Phase 3: all 128 threads (one feature dim each) gather
// 512 B e-rows (L2-resident) with 4 independent accumulators.
__global__ __launch_bounds__(128) void masked_mean_gather(
    const void* __restrict__ pred, const void* __restrict__ succ,
    const void* __restrict__ same, const float* __restrict__ enc,
    float* __restrict__ P, float* __restrict__ S, float* __restrict__ T,
    const int* __restrict__ esz_p) {
  const int row = blockIdx.x;   // b*2048 + i
  const int mid = blockIdx.y;   // 0=pred, 1=succ, 2=same
  const int t = threadIdx.x;
  const int lane = t & 63;
  const int wave = t >> 6;
  const int esz = *esz_p;
  const void* mbase = (mid == 0) ? pred : (mid == 1) ? succ : same;
  float* outp = (mid == 0) ? P : (mid == 1) ? S : T;

  __shared__ unsigned long long words[32];
  if (esz == 4) {
    const unsigned int* mrow = (const unsigned int*)mbase + (size_t)row * 2048;
    for (int w = wave * 16; w < wave * 16 + 16; ++w) {
      unsigned long long bits = __ballot(mrow[w * 64 + lane] != 0u);
      if (lane == 0) words[w] = bits;
    }
  } else {
    const unsigned char* mrow = (const unsigned char*)mbase + (size_t)row * 2048;
    for (int w = wave * 16; w < wave * 16 + 16; ++w) {
      unsigned long long bits = __ballot(mrow[w * 64 + lane] != 0);
      if (lane == 0) words[w] = bits;
    }
  }
  __syncthreads();

  __shared__ int list[2048];
  __shared__ int cnt_s;
  if (t == 0) {
    int n = 0;
    for (int w = 0; w < 32; ++w) {
      unsigned long long bits = words[w];
      int base = w * 64;
      while (bits) {
        int p = __builtin_ctzll(bits);
        bits &= bits - 1;
        list[n++] = base + p;
      }
    }
    cnt_s = n;
  }
  __syncthreads();

  const int n = cnt_s;
  const int b = row >> 11;  // 2048 rows per batch
  // e_pred/e_succ/e_same live at enc cols 128*(mid+1) .. +128
  const float* erow = enc + ((size_t)b * 2048) * 512 + 128 * (mid + 1) + t;
  float a0 = 0.f, a1 = 0.f, a2 = 0.f, a3 = 0.f;
  int k = 0;
  for (; k + 4 <= n; k += 4) {
    int j0 = list[k], j1 = list[k + 1], j2 = list[k + 2], j3 = list[k + 3];
    a0 += erow[(size_t)j0 * 512];
    a1 += erow[(size_t)j1 * 512];
    a2 += erow[(size_t)j2 * 512];
    a3 += erow[(size_t)j3 * 512];
  }
  for (; k < n; ++k) a0 += erow[(size_t)list[k] * 512];
  float acc = (a0 + a1) + (a2 + a3);
  float deg = (float)(n > 0 ? n : 1);
  outp[(size_t)row * 128 + t] = acc / deg;
}

// ---------------------------------------------------------------------------
// f32 tiled GEMM with bias: C[M,N] = A[M,K] @ B[K,N] + bias. A is a virtual
// concat of up to 3 sources, each owning a 128-wide K segment (seg = k>>7),
// with independent leading strides (so "origin" can be read in place from the
// enc buffer with stride 512). BM=BN=64, BK=32, 256 threads, 4x4 acc/thread.
__global__ __launch_bounds__(256) void gemm_bias(
    const float* __restrict__ A0, int lda0,
    const float* __restrict__ A1, int lda1,
    const float* __restrict__ A2, int lda2,
    const float* __restrict__ Bw, const float* __restrict__ bias,
    float* __restrict__ C, int N, int K) {
  __shared__ float As[BK][BM + 4];  // +4 pad: keeps float4 alignment, breaks stride
  __shared__ float Bs[BK][BN];
  const int bm = blockIdx.x * BM;
  const int bn = blockIdx.y * BN;
  const int t = threadIdx.x;
  const int tx = t & 15;   // n dir
  const int ty = t >> 4;   // m dir
  float acc[4][4] = {};

  for (int k0 = 0; k0 < K; k0 += BK) {
    const int seg = k0 >> 7;
    const float* Ap = (seg == 0) ? A0 : (seg == 1) ? A1 : A2;
    const int lda = (seg == 0) ? lda0 : (seg == 1) ? lda1 : lda2;
    const int koff = k0 & 127;
    {  // A tile: 64 rows x 32 k, stored transposed As[k][m]
      const int kk = t & 31;
      const int r0 = t >> 5;
#pragma unroll
      for (int p = 0; p < 8; ++p) {
        const int r = r0 + p * 8;
        As[kk][r] = Ap[(size_t)(bm + r) * lda + koff + kk];
      }
    }
    {  // B tile: 32 k x 64 n
      const int nn = t & 63;
      const int kr0 = t >> 6;
#pragma unroll
      for (int p = 0; p < 8; ++p) {
        const int kk = kr0 + p * 4;
        Bs[kk][nn] = Bw[(size_t)(k0 + kk) * N + bn + nn];
      }
    }
    __syncthreads();
#pragma unroll
    for (int kk = 0; kk < BK; ++kk) {
      float4 av = *(const float4*)&As[kk][ty * 4];
      float4 bv = *(const float4*)&Bs[kk][tx * 4];
      float a[4] = {av.x, av.y, av.z, av.w};
      float b[4] = {bv.x, bv.y, bv.z, bv.w};
#pragma unroll
      for (int i = 0; i < 4; ++i)
#pragma unroll
        for (int j = 0; j < 4; ++j) acc[i][j] += a[i] * b[j];
    }
    __syncthreads();
  }

#pragma unroll
  for (int i = 0; i < 4; ++i) {
    const int row = bm + ty * 4 + i;
    const int col = bn + tx * 4;
    float4 v;
    v.x = acc[i][0] + bias[col + 0];
    v.y = acc[i][1] + bias[col + 1];
    v.z = acc[i][2] + bias[col + 2];
    v.w = acc[i][3] + bias[col + 3];
    *(float4*)&C[(size_t)row * N + col] = v;
  }
}

// ---------------------------------------------------------------------------
extern "C" void kernel_launch(void* const* d_in, const int* in_sizes, int n_in,
                              void* d_out, int out_size, void* d_ws,
                              size_t ws_size, hipStream_t stream) {
  const float* features = (const float*)d_in[0];
  const void* pred = d_in[1];
  const void* succ = d_in[2];
  const void* same = d_in[3];
  const float* W_enc  = (const float*)d_in[4];
  const float* b_enc  = (const float*)d_in[5];
  const float* W_space = (const float*)d_in[6];
  const float* b_space = (const float*)d_in[7];
  const float* W_same = (const float*)d_in[8];
  const float* b_same = (const float*)d_in[9];
  const float* W_mix  = (const float*)d_in[10];
  const float* b_mix  = (const float*)d_in[11];
  float* out = (float*)d_out;

  const size_t M = 16384;  // B*C
  float* ws = (float*)d_ws;
  float* enc = ws;                 // [16384, 512]
  float* P = enc + M * 512;        // pred_f  [16384, 128]
  float* S = P + M * 128;          // succ_f
  float* T = S + M * 128;          // same_f
  float* X = T + M * 128;          // space_mixed
  float* Y = X + M * 128;          // same_mixed
  int* esz = (int*)(Y + M * 128);  // mask element-width flag

  detect_mask_width<<<1, 256, 0, stream>>>((const unsigned int*)pred, esz);

  // enc = features @ W_enc + b_enc   [16384,128]@[128,512]
  gemm_bias<<<dim3(256, 8), 256, 0, stream>>>(
      features, 128, nullptr, 0, nullptr, 0, W_enc, b_enc, enc, 512, 128);

  // pred_f / succ_f / same_f
  masked_mean_gather<<<dim3(16384, 3), 128, 0, stream>>>(
      pred, succ, same, enc, P, S, T, esz);

  // X = [pred_f | origin | succ_f] @ W_space + b_space   (origin = enc cols 0:128)
  gemm_bias<<<dim3(256, 2), 256, 0, stream>>>(
      P, 128, enc, 512, S, 128, W_space, b_space, X, 128, 384);

  // Y = [origin | same_f] @ W_same + b_same
  gemm_bias<<<dim3(256, 2), 256, 0, stream>>>(
      enc, 512, T, 128, nullptr, 0, W_same, b_same, Y, 128, 256);

  // out = [X | Y] @ W_mix + b_mix
  gemm_bias<<<dim3(256, 2), 256, 0, stream>>>(
      X, 128, Y, 128, nullptr, 0, W_mix, b_mix, out, 128, 256);
}

// Round 2
// 452.574 us; speedup vs baseline: 1.5646x; 1.5646x over previous
//
#include <hip/hip_runtime.h>
#include <stdint.h>

typedef unsigned int uint;
typedef unsigned short ushort;
typedef unsigned char uchar;
typedef __attribute__((ext_vector_type(8))) short bf16x8;
typedef __attribute__((ext_vector_type(4))) float f32x4;

__device__ __forceinline__ ushort f2bf(float f) {
  uint u = __builtin_bit_cast(uint, f);
  return (ushort)((u + 0x7FFFu + ((u >> 16) & 1u)) >> 16);
}

// ---------------------------------------------------------------------------
// Mask element width detection (4-byte int/float vs 1-byte bool).
__global__ __launch_bounds__(256) void k_detect(
    const uint* __restrict__ m, int* __restrict__ esz_out) {
  __shared__ int s_ok;
  if (threadIdx.x == 0) s_ok = 1;
  __syncthreads();
  int ok = 1;
  for (int i = 0; i < 64; ++i) {
    uint v = m[(size_t)threadIdx.x * 64 + i];
    if (!(v == 0u || v == 1u || v == 0x3F800000u)) ok = 0;
  }
  if (!ok) atomicAnd(&s_ok, 0);
  __syncthreads();
  if (threadIdx.x == 0) *esz_out = s_ok ? 4 : 1;
}

// ---------------------------------------------------------------------------
// features f32 -> bf16 (row-major [16384][128])
__global__ __launch_bounds__(256) void k_cvt_feat(
    const float4* __restrict__ in, ushort* __restrict__ out) {
  for (int i = blockIdx.x * 256 + threadIdx.x; i < 524288; i += 65536) {
    float4 v = in[i];
    ushort4 o;
    o.x = f2bf(v.x); o.y = f2bf(v.y); o.z = f2bf(v.z); o.w = f2bf(v.w);
    *(ushort4*)&out[(size_t)i * 4] = o;
  }
}

// ---------------------------------------------------------------------------
// Transpose all weights to bf16 [n][k] layout.
__global__ __launch_bounds__(256) void k_twt(
    const float* __restrict__ We, const float* __restrict__ Ws,
    const float* __restrict__ Wm, const float* __restrict__ Wx,
    ushort* __restrict__ Te, ushort* __restrict__ Ts,
    ushort* __restrict__ Tm, ushort* __restrict__ Tx) {
  int i = blockIdx.x * 256 + threadIdx.x;
  if (i < 65536) { int n = i >> 7, k = i & 127; Te[i] = f2bf(We[k * 512 + n]); return; }
  i -= 65536;
  if (i < 49152) { int n = i / 384, k = i - n * 384; Ts[i] = f2bf(Ws[k * 128 + n]); return; }
  i -= 49152;
  if (i < 32768) { int n = i >> 8, k = i & 255; Tm[i] = f2bf(Wm[k * 128 + n]); return; }
  i -= 32768;
  if (i < 32768) { int n = i >> 8, k = i & 255; Tx[i] = f2bf(Wx[k * 128 + n]); return; }
}

// ---------------------------------------------------------------------------
// MFMA inner step: 64x128 tile, 4 waves (wave quadrant 32x64), BK=64.
// As [64][72] bf16 row-major [m][k]; Bs [128][72] bf16 [n][k].
__device__ __forceinline__ void mfma_tiles(const ushort* As, const ushort* Bs,
                                           int m0w, int n0w, int lr, int quad,
                                           f32x4 acc[2][4]) {
#pragma unroll
  for (int kc = 0; kc < 2; ++kc) {
    bf16x8 a[2], b[4];
#pragma unroll
    for (int i = 0; i < 2; ++i)
      a[i] = *(const bf16x8*)&As[(m0w + i * 16 + lr) * 72 + kc * 32 + quad * 8];
#pragma unroll
    for (int j = 0; j < 4; ++j)
      b[j] = *(const bf16x8*)&Bs[(n0w + j * 16 + lr) * 72 + kc * 32 + quad * 8];
#pragma unroll
    for (int i = 0; i < 2; ++i)
#pragma unroll
      for (int j = 0; j < 4; ++j)
        acc[i][j] = __builtin_amdgcn_mfma_f32_16x16x32_bf16(a[i], b[j], acc[i][j], 0, 0, 0);
  }
}

// ---------------------------------------------------------------------------
// Encoder GEMM: feat_bf[16384,128] @ WT_enc -> origin (row-major) + 3 eT
// (transposed [128][16384]) with bias. Tile 64x128, grid(256, 4).
__global__ __launch_bounds__(256) void k_enc(
    const ushort* __restrict__ featbf, const ushort* __restrict__ WTe,
    const float* __restrict__ bias, ushort* __restrict__ origin,
    ushort* __restrict__ eT0, ushort* __restrict__ eT1, ushort* __restrict__ eT2) {
  __shared__ ushort As[64 * 72];
  __shared__ ushort Bs[128 * 72];
  const int t = threadIdx.x;
  const int gm0 = blockIdx.x * 64;
  const int y = blockIdx.y;
  const ushort* Bsrc = WTe + (size_t)y * 128 * 128;
  const int lane = t & 63, wave = t >> 6;
  const int m0w = (wave >> 1) * 32, n0w = (wave & 1) * 64;
  const int quad = lane >> 4, lr = lane & 15;
  const int am = t >> 2, aq = t & 3;
  const int bn = t >> 1, bh = t & 1;
  f32x4 acc[2][4] = {};
  for (int k0 = 0; k0 < 128; k0 += 64) {
    const ushort* asrc = featbf + (size_t)(gm0 + am) * 128 + k0 + aq * 16;
    bf16x8 av0 = *(const bf16x8*)asrc;
    bf16x8 av1 = *(const bf16x8*)(asrc + 8);
    const ushort* bsrc = Bsrc + (size_t)bn * 128 + k0 + bh * 32;
    bf16x8 bv0 = *(const bf16x8*)bsrc;
    bf16x8 bv1 = *(const bf16x8*)(bsrc + 8);
    bf16x8 bv2 = *(const bf16x8*)(bsrc + 16);
    bf16x8 bv3 = *(const bf16x8*)(bsrc + 24);
    *(bf16x8*)&As[am * 72 + aq * 16] = av0;
    *(bf16x8*)&As[am * 72 + aq * 16 + 8] = av1;
    *(bf16x8*)&Bs[bn * 72 + bh * 32] = bv0;
    *(bf16x8*)&Bs[bn * 72 + bh * 32 + 8] = bv1;
    *(bf16x8*)&Bs[bn * 72 + bh * 32 + 16] = bv2;
    *(bf16x8*)&Bs[bn * 72 + bh * 32 + 24] = bv3;
    __syncthreads();
    mfma_tiles(As, Bs, m0w, n0w, lr, quad, acc);
    __syncthreads();
  }
  ushort* eT = (y == 1) ? eT0 : (y == 2) ? eT1 : eT2;
#pragma unroll
  for (int i = 0; i < 2; ++i)
#pragma unroll
    for (int j = 0; j < 4; ++j)
#pragma unroll
      for (int r = 0; r < 4; ++r) {
        int m = gm0 + m0w + i * 16 + quad * 4 + r;
        int n = n0w + j * 16 + lr;
        ushort h = f2bf(acc[i][j][r] + bias[y * 128 + n]);
        if (y == 0) origin[(size_t)m * 128 + n] = h;
        else eT[(size_t)n * 16384 + m] = h;
      }
}

// ---------------------------------------------------------------------------
// Masked mean as dense MFMA GEMM with on-the-fly int->bf16 mask conversion
// and fused degree popcount. Grid (32 mtiles, 8 batches, 3 masks).
__global__ __launch_bounds__(256) void k_mm(
    const void* __restrict__ mp, const void* __restrict__ ms, const void* __restrict__ mt,
    const ushort* __restrict__ eT0, const ushort* __restrict__ eT1, const ushort* __restrict__ eT2,
    ushort* __restrict__ P, ushort* __restrict__ S, ushort* __restrict__ T,
    const int* __restrict__ esz_p) {
  __shared__ ushort As[64 * 72];
  __shared__ ushort Bs[128 * 72];
  __shared__ uint degs[64];
  const int t = threadIdx.x;
  const int mtile = blockIdx.x, b = blockIdx.y, mid = blockIdx.z;
  const void* mask = (mid == 0) ? mp : (mid == 1) ? ms : mt;
  const ushort* eT = (mid == 0) ? eT0 : (mid == 1) ? eT1 : eT2;
  ushort* outp = (mid == 0) ? P : (mid == 1) ? S : T;
  const int esz = *esz_p;
  if (t < 64) degs[t] = 0;
  const size_t rowbase = (size_t)b * 2048 + mtile * 64;
  const int lane = t & 63, wave = t >> 6;
  const int m0w = (wave >> 1) * 32, n0w = (wave & 1) * 64;
  const int quad = lane >> 4, lr = lane & 15;
  const int am = t >> 2, aq = t & 3;
  const int bn = t >> 1, bh = t & 1;
  const ushort* bsrc_base = eT + (size_t)bn * 16384 + (size_t)b * 2048 + bh * 32;
  f32x4 acc[2][4] = {};
  int cnt = 0;
  for (int k0 = 0; k0 < 2048; k0 += 64) {
    bf16x8 o0, o1;
    if (esz == 4) {
      const uint* p = (const uint*)mask + (rowbase + am) * 2048 + k0 + aq * 16;
      uint w[16];
      *(uint4*)&w[0] = *(const uint4*)p;
      *(uint4*)&w[4] = *(const uint4*)(p + 4);
      *(uint4*)&w[8] = *(const uint4*)(p + 8);
      *(uint4*)&w[12] = *(const uint4*)(p + 12);
#pragma unroll
      for (int e = 0; e < 8; ++e) { int nz = (w[e] != 0u); o0[e] = nz ? (short)0x3F80 : (short)0; cnt += nz; }
#pragma unroll
      for (int e = 0; e < 8; ++e) { int nz = (w[e + 8] != 0u); o1[e] = nz ? (short)0x3F80 : (short)0; cnt += nz; }
    } else {
      const uchar* p = (const uchar*)mask + (rowbase + am) * 2048 + k0 + aq * 16;
      uint4 wb = *(const uint4*)p;
      uint arr[4] = {wb.x, wb.y, wb.z, wb.w};
#pragma unroll
      for (int e = 0; e < 8; ++e) { int nz = (((arr[e >> 2] >> ((e & 3) * 8)) & 0xFFu) != 0u); o0[e] = nz ? (short)0x3F80 : (short)0; cnt += nz; }
#pragma unroll
      for (int e = 0; e < 8; ++e) { int ee = e + 8; int nz = (((arr[ee >> 2] >> ((ee & 3) * 8)) & 0xFFu) != 0u); o1[e] = nz ? (short)0x3F80 : (short)0; cnt += nz; }
    }
    const ushort* bsrc = bsrc_base + k0;
    bf16x8 bv0 = *(const bf16x8*)bsrc;
    bf16x8 bv1 = *(const bf16x8*)(bsrc + 8);
    bf16x8 bv2 = *(const bf16x8*)(bsrc + 16);
    bf16x8 bv3 = *(const bf16x8*)(bsrc + 24);
    *(bf16x8*)&As[am * 72 + aq * 16] = o0;
    *(bf16x8*)&As[am * 72 + aq * 16 + 8] = o1;
    *(bf16x8*)&Bs[bn * 72 + bh * 32] = bv0;
    *(bf16x8*)&Bs[bn * 72 + bh * 32 + 8] = bv1;
    *(bf16x8*)&Bs[bn * 72 + bh * 32 + 16] = bv2;
    *(bf16x8*)&Bs[bn * 72 + bh * 32 + 24] = bv3;
    __syncthreads();
    mfma_tiles(As, Bs, m0w, n0w, lr, quad, acc);
    __syncthreads();
  }
  atomicAdd(&degs[am], (uint)cnt);
  __syncthreads();
#pragma unroll
  for (int i = 0; i < 2; ++i)
#pragma unroll
    for (int r = 0; r < 4; ++r) {
      int ml = m0w + i * 16 + quad * 4 + r;
      uint d = degs[ml];
      float inv = 1.0f / (float)(d > 0u ? d : 1u);
#pragma unroll
      for (int j = 0; j < 4; ++j) {
        int n = n0w + j * 16 + lr;
        outp[(rowbase + ml) * 128 + n] = f2bf(acc[i][j][r] * inv);
      }
    }
}

// ---------------------------------------------------------------------------
// Generic MFMA GEMM: A = virtual concat of up to 3 bf16 [M,128] sources along
// K, B = WT bf16 [128][K], + bias. Out row-major [M,128] bf16 or f32.
__global__ __launch_bounds__(256) void k_gemm(
    const ushort* __restrict__ A0, const ushort* __restrict__ A1,
    const ushort* __restrict__ A2, const ushort* __restrict__ Bsrc,
    int bstride, int K, const float* __restrict__ bias,
    void* __restrict__ out, int out_f32) {
  __shared__ ushort As[64 * 72];
  __shared__ ushort Bs[128 * 72];
  const int t = threadIdx.x;
  const int gm0 = blockIdx.x * 64;
  const int lane = t & 63, wave = t >> 6;
  const int m0w = (wave >> 1) * 32, n0w = (wave & 1) * 64;
  const int quad = lane >> 4, lr = lane & 15;
  const int am = t >> 2, aq = t & 3;
  const int bn = t >> 1, bh = t & 1;
  f32x4 acc[2][4] = {};
  for (int k0 = 0; k0 < K; k0 += 64) {
    const int seg = k0 >> 7;
    const ushort* Ap = (seg == 0) ? A0 : (seg == 1) ? A1 : A2;
    const ushort* asrc = Ap + (size_t)(gm0 + am) * 128 + (k0 & 127) + aq * 16;
    bf16x8 av0 = *(const bf16x8*)asrc;
    bf16x8 av1 = *(const bf16x8*)(asrc + 8);
    const ushort* bsrc = Bsrc + (size_t)bn * bstride + k0 + bh * 32;
    bf16x8 bv0 = *(const bf16x8*)bsrc;
    bf16x8 bv1 = *(const bf16x8*)(bsrc + 8);
    bf16x8 bv2 = *(const bf16x8*)(bsrc + 16);
    bf16x8 bv3 = *(const bf16x8*)(bsrc + 24);
    *(bf16x8*)&As[am * 72 + aq * 16] = av0;
    *(bf16x8*)&As[am * 72 + aq * 16 + 8] = av1;
    *(bf16x8*)&Bs[bn * 72 + bh * 32] = bv0;
    *(bf16x8*)&Bs[bn * 72 + bh * 32 + 8] = bv1;
    *(bf16x8*)&Bs[bn * 72 + bh * 32 + 16] = bv2;
    *(bf16x8*)&Bs[bn * 72 + bh * 32 + 24] = bv3;
    __syncthreads();
    mfma_tiles(As, Bs, m0w, n0w, lr, quad, acc);
    __syncthreads();
  }
#pragma unroll
  for (int i = 0; i < 2; ++i)
#pragma unroll
    for (int j = 0; j < 4; ++j)
#pragma unroll
      for (int r = 0; r < 4; ++r) {
        int m = gm0 + m0w + i * 16 + quad * 4 + r;
        int n = n0w + j * 16 + lr;
        float v = acc[i][j][r] + bias[n];
        if (out_f32) ((float*)out)[(size_t)m * 128 + n] = v;
        else ((ushort*)out)[(size_t)m * 128 + n] = f2bf(v);
      }
}

// ---------------------------------------------------------------------------
extern "C" void kernel_launch(void* const* d_in, const int* in_sizes, int n_in,
                              void* d_out, int out_size, void* d_ws,
                              size_t ws_size, hipStream_t stream) {
  const float* features = (const float*)d_in[0];
  const void* pred = d_in[1];
  const void* succ = d_in[2];
  const void* same = d_in[3];
  const float* W_enc = (const float*)d_in[4];
  const float* b_enc = (const float*)d_in[5];
  const float* W_space = (const float*)d_in[6];
  const float* b_space = (const float*)d_in[7];
  const float* W_same = (const float*)d_in[8];
  const float* b_same = (const float*)d_in[9];
  const float* W_mix = (const float*)d_in[10];
  const float* b_mix = (const float*)d_in[11];

  const size_t M = 16384;
  ushort* w = (ushort*)d_ws;
  ushort* feat_bf = w;  w += M * 128;
  ushort* WT_enc = w;   w += 512 * 128;
  ushort* WT_space = w; w += 128 * 384;
  ushort* WT_same = w;  w += 128 * 256;
  ushort* WT_mix = w;   w += 128 * 256;
  ushort* origin = w;   w += M * 128;
  ushort* eT0 = w;      w += M * 128;
  ushort* eT1 = w;      w += M * 128;
  ushort* eT2 = w;      w += M * 128;
  ushort* P = w;        w += M * 128;
  ushort* S = w;        w += M * 128;
  ushort* T = w;        w += M * 128;
  ushort* X = w;        w += M * 128;
  ushort* Y = w;        w += M * 128;
  int* esz = (int*)w;

  k_detect<<<1, 256, 0, stream>>>((const uint*)pred, esz);
  k_cvt_feat<<<256, 256, 0, stream>>>((const float4*)features, feat_bf);
  k_twt<<<704, 256, 0, stream>>>(W_enc, W_space, W_same, W_mix,
                                 WT_enc, WT_space, WT_same, WT_mix);
  k_enc<<<dim3(256, 4), 256, 0, stream>>>(feat_bf, WT_enc, b_enc,
                                          origin, eT0, eT1, eT2);
  k_mm<<<dim3(32, 8, 3), 256, 0, stream>>>(pred, succ, same, eT0, eT1, eT2,
                                           P, S, T, esz);
  // X = [P | origin | S] @ W_space + b_space
  k_gemm<<<256, 256, 0, stream>>>(P, origin, S, WT_space, 384, 384,
                                  b_space, X, 0);
  // Y = [origin | T] @ W_same + b_same
  k_gemm<<<256, 256, 0, stream>>>(origin, T, nullptr, WT_same, 256, 256,
                                  b_same, Y, 0);
  // out = [X | Y] @ W_mix + b_mix  (f32)
  k_gemm<<<256, 256, 0, stream>>>(X, Y, nullptr, WT_mix, 256, 256,
                                  b_mix, d_out, 1);
}